// Round 10
// baseline (802.599 us; speedup 1.0000x reference)
//
#include <hip/hip_runtime.h>
#include <cstdint>
#include <cstddef>

// GNN (GGNN) on MI355X. Inputs fp32, output fp32; internal bf16 MFMA w/ fp32
// accum (passing since round 6: absmax 0.0117 vs threshold 0.028).
// ROUND 10: AV operand-pairing — one block computes BOTH inM@nodes and
// outM@nodes for the same (m,d,batch) tile. B-tile (nodesT) staged once and
// its register fragments reused for 2x MFMAs: 12 ds_read_b128 per 32 MFMA
// (was 16 per 32 across two blocks), DMA bytes/MFMA 0.75KB (was 1KB),
// barrier-pairs per output halved. Everything else = round-9 verified state
// (BK=32, conflict-free chunk swizzle [R9: conflicts 6.29M->0], XCD banding
// [R8: FETCH 162->72MB], global_load_lds w16 [R7], fused converts).
// Per step: T=nodes^T; av=[inM@nodes | outM@nodes]; u3=nodes@w3u^T+b3u;
// [z|r|h]pre=av@[w3w|w4w|w5w]^T (epilogue: gates, rf=r*nodes);
// t=rf@w5u^T; nodes=(1-z)*nodes+z*tanh(hpre+t+b5u).
// Output: nodes (fp32) ++ in_matrix (fp32 passthrough).

#define B_ 16
#define N_ 1024
#define D_ 512
#define S_ (B_ * N_)      // 16384
#define TWO_D 1024

typedef __attribute__((ext_vector_type(8))) short short8;
typedef __attribute__((ext_vector_type(4))) short s16x4;
typedef __attribute__((ext_vector_type(4))) float f32x4;

#define EPI_U3  1
#define EPI_BIG 2
#define EPI_G4  3

__device__ __forceinline__ float bf2f(short u) {
  union { unsigned int i; float f; } v;
  v.i = ((unsigned int)(unsigned short)u) << 16;
  return v.f;
}
__device__ __forceinline__ short f2bf(float f) {
  union { float f; unsigned int i; } v;
  v.f = f;
  unsigned int x = v.i;
  unsigned int r = (x + 0x7fffu + ((x >> 16) & 1u)) >> 16;  // RTNE
  return (short)(unsigned short)r;
}
__device__ __forceinline__ float fast_sigmoid(float x) {
  return __builtin_amdgcn_rcpf(1.f + __expf(-x));
}
__device__ __forceinline__ float fast_tanh(float x) {
  const float t = __expf(-2.f * fabsf(x));
  const float th = (1.f - t) * __builtin_amdgcn_rcpf(1.f + t);
  return __builtin_copysignf(th, x);
}

// Async global->LDS DMA, 16 bytes/lane; LDS dest = wave-uniform base+lane*16.
__device__ __forceinline__ void gload16(const void* g, void* l) {
  __builtin_amdgcn_global_load_lds(
      (__attribute__((address_space(1))) void*)g,
      (__attribute__((address_space(3))) void*)l, 16, 0, 0);
}

// ---------------- paired adjacency GEMM -----------------
// av[b, m, 0:512] = inM[m,:] @ nodes[b,:,d],  av[b, m, 512:1024] = outM @ ...
// One block: 128(m) x 128(d) for BOTH matrices of one batch. BK=32.
// 4 waves 2x2, wave 64x64 per matrix, B-frags reused across the two acc sets.
__global__ __launch_bounds__(256) void gemm_av2(
    const short* inM, const short* outM, const short* T, short* av, int C) {
  __shared__ __align__(16) short lds_ai[128 * 32];  // 8 KB inM tile
  __shared__ __align__(16) short lds_ao[128 * 32];  // 8 KB outM tile
  __shared__ __align__(16) short lds_b[128 * 32];   // 8 KB nodesT tile

  const int tid = threadIdx.x;
  const int lane = tid & 63;
  const int wave = tid >> 6;
  const int wr = wave >> 1, wc = wave & 1;

  // XCD banding: contiguous batch range per XCD (total blocks = C*32, /8)
  int bx = blockIdx.x, by = blockIdx.y, bz = blockIdx.z;
  {
    const int total = gridDim.x * gridDim.y * gridDim.z;
    const int id = (bz * gridDim.y + by) * gridDim.x + bx;
    const int a = id & 7, m = id >> 3;
    const int l = a * (total >> 3) + m;
    bz = l >> 5;          // gy*gx = 32
    by = (l >> 2) & 7;
    bx = l & 3;
  }
  const int m0 = by * 128;        // adjacency row tile
  const int n0 = bx * 128;        // d tile
  const int b_ = bz;              // batch

  const short* Bt = T + (size_t)b_ * ((size_t)D_ * N_);

  f32x4 acc_i[4][4], acc_o[4][4];
#pragma unroll
  for (int i = 0; i < 4; i++)
#pragma unroll
    for (int j = 0; j < 4; j++) {
      acc_i[i][j] = (f32x4){0.f, 0.f, 0.f, 0.f};
      acc_o[i][j] = (f32x4){0.f, 0.f, 0.f, 0.f};
    }

  const int ar = tid >> 2;                    // row-slot 0..63
  const int sc = tid & 3;                     // stored chunk position
  const int qg = (sc - (ar >> 1)) & 3;        // global k-chunk (conflict-free)
  const int ac = qg * 8;
  char* lai = (char*)lds_ai + tid * 16;
  char* lao = (char*)lds_ao + tid * 16;
  char* lb = (char*)lds_b + tid * 16;
  const short* gi0 = inM + (size_t)(m0 + ar) * N_ + ac;
  const short* gi1 = inM + (size_t)(m0 + ar + 64) * N_ + ac;
  const short* go0 = outM + (size_t)(m0 + ar) * N_ + ac;
  const short* go1 = outM + (size_t)(m0 + ar + 64) * N_ + ac;
  const short* gb0 = Bt + (size_t)(n0 + ar) * N_ + ac;
  const short* gb1 = Bt + (size_t)(n0 + ar + 64) * N_ + ac;

  const int lm = lane & 15;
  const int qq = lane >> 4;

  for (int k0 = 0; k0 < N_; k0 += 32) {
    __syncthreads();
    gload16(gi0 + k0, lai);
    gload16(gi1 + k0, lai + 4096);
    gload16(go0 + k0, lao);
    gload16(go1 + k0, lao + 4096);
    gload16(gb0 + k0, lb);
    gload16(gb1 + k0, lb + 4096);
    __syncthreads();

    short8 ai[4], ao[4], bfr[4];
#pragma unroll
    for (int i = 0; i < 4; i++) {
      const int Ra = wr * 64 + i * 16 + lm;
      const int o = Ra * 64 + (((qq + (Ra >> 1)) & 3) << 4);
      ai[i] = *(const short8*)((const char*)lds_ai + o);
      ao[i] = *(const short8*)((const char*)lds_ao + o);
    }
#pragma unroll
    for (int j = 0; j < 4; j++) {
      const int Rb = wc * 64 + j * 16 + lm;
      bfr[j] = *(const short8*)((const char*)lds_b + Rb * 64 +
                                (((qq + (Rb >> 1)) & 3) << 4));
    }
#pragma unroll
    for (int i = 0; i < 4; i++)
#pragma unroll
      for (int j = 0; j < 4; j++) {
        acc_i[i][j] = __builtin_amdgcn_mfma_f32_16x16x32_bf16(
            ai[i], bfr[j], acc_i[i][j], 0, 0, 0);
        acc_o[i][j] = __builtin_amdgcn_mfma_f32_16x16x32_bf16(
            ao[i], bfr[j], acc_o[i][j], 0, 0, 0);
      }
  }

  const int r0 = (lane >> 4) * 4;
#pragma unroll
  for (int i = 0; i < 4; i++)
#pragma unroll
    for (int j = 0; j < 4; j++)
#pragma unroll
      for (int r = 0; r < 4; r++) {
        const int grow = m0 + wr * 64 + i * 16 + r0 + r;
        const int gcol = n0 + wc * 64 + j * 16 + lm;
        const size_t base = ((size_t)(b_ * N_ + grow)) * TWO_D;
        av[base + gcol] = f2bf(acc_i[i][j][r]);
        av[base + D_ + gcol] = f2bf(acc_o[i][j][r]);
      }
}

// ---------------- generic NT GEMM (U3 / BIG / G4) -----------------
// C[M,Nc] = A[M,K] * Bw[Nc,K]^T, 128x128 tile, BK=32, conflict-free swizzle.
template <int EPI>
__global__ __launch_bounds__(256) void gemm_nt(
    const short* A, int lda,
    const short* Bw, const short* Bw2, const short* Bw3, int ldb, int K,
    const float* bias0, const float* bias1, const float* bias2,
    const short* u3, const short* fcur,   // may alias out0 (in-place G4)
    const short* hvp, const short* zvp,
    short* out0, short* out1, short* out2,
    float* outf) {
  __shared__ __align__(16) short lds_a[128 * 32];
  __shared__ __align__(16) short lds_b[128 * 32];

  const int tid = threadIdx.x;
  const int lane = tid & 63;
  const int wave = tid >> 6;
  const int wr = wave >> 1, wc = wave & 1;

  int bx = blockIdx.x, by = blockIdx.y;
  {
    const int gx = gridDim.x, gy = gridDim.y;
    if ((gy & 7) == 0) {   // y-band per XCD (A-row reuse)
      const int id = by * gx + bx;
      const int a = id & 7;
      const int m = id >> 3;
      const int per = gy >> 3;
      by = a * per + m / gx;
      bx = m % gx;
    }
  }
  const int m0 = by * 128;
  const int n0 = bx * 128;

  const short* Beff = Bw;
  int nb0 = n0;
  if constexpr (EPI == EPI_BIG) {
    if (n0 < 512) { Beff = Bw; nb0 = n0; }
    else if (n0 < 1024) { Beff = Bw2; nb0 = n0 - 512; }
    else { Beff = Bw3; nb0 = n0 - 1024; }
  }

  f32x4 acc[4][4];
#pragma unroll
  for (int i = 0; i < 4; i++)
#pragma unroll
    for (int j = 0; j < 4; j++) acc[i][j] = (f32x4){0.f, 0.f, 0.f, 0.f};

  const int ar = tid >> 2;
  const int sc = tid & 3;
  const int qg = (sc - (ar >> 1)) & 3;
  const int ac = qg * 8;
  char* la = (char*)lds_a + tid * 16;
  char* lb = (char*)lds_b + tid * 16;
  const short* ga0 = A + (size_t)(m0 + ar) * lda + ac;
  const short* ga1 = A + (size_t)(m0 + ar + 64) * lda + ac;
  const short* gb0 = Beff + (size_t)(nb0 + ar) * ldb + ac;
  const short* gb1 = Beff + (size_t)(nb0 + ar + 64) * ldb + ac;

  const int lm = lane & 15;
  const int qq = lane >> 4;

  for (int k0 = 0; k0 < K; k0 += 32) {
    __syncthreads();
    gload16(ga0 + k0, la);
    gload16(ga1 + k0, la + 4096);
    gload16(gb0 + k0, lb);
    gload16(gb1 + k0, lb + 4096);
    __syncthreads();

    short8 af[4], bfr[4];
#pragma unroll
    for (int i = 0; i < 4; i++) {
      const int Ra = wr * 64 + i * 16 + lm;
      af[i] = *(const short8*)((const char*)lds_a + Ra * 64 +
                               (((qq + (Ra >> 1)) & 3) << 4));
    }
#pragma unroll
    for (int j = 0; j < 4; j++) {
      const int Rb = wc * 64 + j * 16 + lm;
      bfr[j] = *(const short8*)((const char*)lds_b + Rb * 64 +
                                (((qq + (Rb >> 1)) & 3) << 4));
    }
#pragma unroll
    for (int i = 0; i < 4; i++)
#pragma unroll
      for (int j = 0; j < 4; j++)
        acc[i][j] = __builtin_amdgcn_mfma_f32_16x16x32_bf16(
            af[i], bfr[j], acc[i][j], 0, 0, 0);
  }

  const int r0 = (lane >> 4) * 4;
#pragma unroll
  for (int i = 0; i < 4; i++) {
#pragma unroll
    for (int j = 0; j < 4; j++) {
#pragma unroll
      for (int r = 0; r < 4; r++) {
        const int grow = m0 + wr * 64 + i * 16 + r0 + r;
        const int gcol = n0 + wc * 64 + j * 16 + lm;
        const float v = acc[i][j][r];
        if constexpr (EPI == EPI_U3) {
          out0[(size_t)grow * D_ + gcol] = f2bf(v + bias0[gcol]);
        } else if constexpr (EPI == EPI_BIG) {
          if (gcol < 512) {
            const size_t sidx = (size_t)grow * D_ + gcol;
            const float x = v + bias0[gcol] + bf2f(u3[sidx]);
            out0[sidx] = f2bf(fast_sigmoid(x));
          } else if (gcol < 1024) {
            const int e = gcol - 512;
            const size_t sidx = (size_t)grow * D_ + e;
            const float x = v + bias1[e] + bf2f(u3[sidx]);
            out1[sidx] = f2bf(fast_sigmoid(x) * bf2f(fcur[sidx]));
          } else {
            const int e = gcol - 1024;
            const size_t sidx = (size_t)grow * D_ + e;
            out2[sidx] = f2bf(v + bias2[e]);
          }
        } else {  // EPI_G4 (in-place: same thread reads then writes sidx)
          const size_t sidx = (size_t)grow * D_ + gcol;
          const float x = bf2f(hvp[sidx]) + v + bias0[gcol];
          const float hv = fast_tanh(x);
          const float z = bf2f(zvp[sidx]);
          const float f = bf2f(fcur[sidx]);
          const float res = (1.f - z) * f + z * hv;
          if (outf) outf[sidx] = res;      // final step: fp32 to d_out
          else out0[sidx] = f2bf(res);     // intermediate: bf16 nodes
        }
      }
    }
  }
}

// bf16 [C][N][D] -> bf16 [C][D][N] transpose.
__global__ void transpose_bnd(const short* __restrict__ in,
                              short* __restrict__ out) {
  __shared__ short tile[32][33];
  const int b = blockIdx.z;
  const int n0 = blockIdx.y * 32;
  const int d0 = blockIdx.x * 32;
  const int tx = threadIdx.x, ty = threadIdx.y;
  const short* ip = in + (size_t)b * N_ * D_;
  short* op = out + (size_t)b * N_ * D_;
#pragma unroll
  for (int yy = ty; yy < 32; yy += 8)
    tile[yy][tx] = ip[(size_t)(n0 + yy) * D_ + d0 + tx];
  __syncthreads();
#pragma unroll
  for (int yy = ty; yy < 32; yy += 8)
    op[(size_t)(d0 + yy) * N_ + n0 + tx] = tile[tx][yy];
}

// One-shot segmented fp32->bf16 convert (8 jobs, grid-stride over v4 elems).
struct CvtJobs {
  const float* src[8];
  short* dst[8];
  int end4[8];
  int tot4;
};
__global__ void cvt_all(CvtJobs j) {
  for (int idx = blockIdx.x * 256 + threadIdx.x; idx < j.tot4;
       idx += gridDim.x * 256) {
    int k = 0, start = 0;
#pragma unroll
    for (int t = 0; t < 8; t++) {
      if (idx >= j.end4[t]) { k = t + 1; start = j.end4[t]; }
    }
    const int rel = idx - start;
    const f32x4 v = ((const f32x4*)j.src[k])[rel];
    s16x4 o;
#pragma unroll
    for (int r = 0; r < 4; r++) o[r] = f2bf(v[r]);
    ((s16x4*)j.dst[k])[rel] = o;
  }
}

extern "C" void kernel_launch(void* const* d_in, const int* in_sizes, int n_in,
                              void* d_out, int out_size, void* d_ws,
                              size_t ws_size, hipStream_t stream) {
  const float* x = (const float*)d_in[0];
  const float* inM = (const float*)d_in[1];
  const float* outM = (const float*)d_in[2];
  const float* w3w = (const float*)d_in[3];
  const float* b3w = (const float*)d_in[4];
  const float* w3u = (const float*)d_in[5];
  const float* b3u = (const float*)d_in[6];
  const float* w4w = (const float*)d_in[7];
  const float* b4w = (const float*)d_in[8];
  const float* w5w = (const float*)d_in[9];
  const float* b5w = (const float*)d_in[10];
  const float* w5u = (const float*)d_in[11];
  const float* b5u = (const float*)d_in[12];
  float* outF = (float*)d_out;   // fp32 output: nodes [S_,D_] ++ in_matrix

  char* ws = (char*)d_ws;
  size_t off = 0;
  auto alloc = [&](size_t elems) {
    short* p = (short*)(ws + off);
    off = (off + elems * 2 + 255) & ~(size_t)255;
    return p;
  };
  short* nodes = alloc((size_t)S_ * D_);           // bf16 recursion state
  short* inMb = alloc((size_t)N_ * N_);
  short* outMb = alloc((size_t)N_ * N_);
  short* w3wb = alloc((size_t)512 * 1024);
  short* w4wb = alloc((size_t)512 * 1024);
  short* w5wb = alloc((size_t)512 * 1024);
  short* w3ub = alloc((size_t)D_ * D_);
  short* w5ub = alloc((size_t)D_ * D_);
  const size_t fixed = off;

  // chunk size C: per-chunk scratch = T+av+u3+zv+rf+hvp = 7*C*N*D bf16
  int C = 1;
  for (int c = 16; c >= 1; c >>= 1) {
    const size_t need = fixed + (size_t)7 * c * N_ * D_ * 2 + 8 * 256;
    if (need <= ws_size) { C = c; break; }
  }
  short* T = alloc((size_t)C * D_ * N_);
  short* av = alloc((size_t)C * N_ * TWO_D);
  short* u3 = alloc((size_t)C * N_ * D_);
  short* zv = alloc((size_t)C * N_ * D_);
  short* rf = alloc((size_t)C * N_ * D_);
  short* hvp = alloc((size_t)C * N_ * D_);

  // --- one fused convert launch: fp32 -> bf16 working set ---
  CvtJobs cj;
  const int xs4 = S_ * D_ / 4, nn4 = N_ * N_ / 4;
  const int dd4 = D_ * D_ / 4, wd4 = 512 * 1024 / 4;
  const float* srcs[8] = {x, inM, outM, w3w, w4w, w5w, w3u, w5u};
  short* dsts[8] = {nodes, inMb, outMb, w3wb, w4wb, w5wb, w3ub, w5ub};
  const int lens[8] = {xs4, nn4, nn4, wd4, wd4, wd4, dd4, dd4};
  int cum = 0;
  for (int i = 0; i < 8; i++) {
    cj.src[i] = srcs[i];
    cj.dst[i] = dsts[i];
    cum += lens[i];
    cj.end4[i] = cum;
  }
  cj.tot4 = cum;
  cvt_all<<<1536, 256, 0, stream>>>(cj);
  // output 1: in_matrix passthrough (fp32 bit copy)
  hipMemcpyAsync(outF + (size_t)S_ * D_, inM, (size_t)N_ * N_ * 4,
                 hipMemcpyDeviceToDevice, stream);

  const dim3 tb32(32, 8);
  const dim3 tg(D_ / 32, N_ / 32, C);
  const dim3 g_av(D_ / 128, N_ / 128, C);        // paired adjacency
  const dim3 g_d(D_ / 128, C * N_ / 128, 1);
  const dim3 g_big(1536 / 128, C * N_ / 128, 1);

  const int nchunks = B_ / C;
  for (int c = 0; c < nchunks; ++c) {
    short* nodes_c = nodes + (size_t)c * C * N_ * D_;
    float* outF_c = outF + (size_t)c * C * N_ * D_;
    for (int step = 0; step < 3; ++step) {
      transpose_bnd<<<tg, tb32, 0, stream>>>(nodes_c, T);
      gemm_av2<<<g_av, 256, 0, stream>>>(inMb, outMb, T, av, C);
      gemm_nt<EPI_U3><<<g_d, 256, 0, stream>>>(
          nodes_c, D_, w3ub, nullptr, nullptr, D_, D_, b3u, nullptr, nullptr,
          nullptr, nullptr, nullptr, nullptr, u3, nullptr, nullptr, nullptr);
      gemm_nt<EPI_BIG><<<g_big, 256, 0, stream>>>(
          av, TWO_D, w3wb, w4wb, w5wb, TWO_D, TWO_D, b3w, b4w, b5w,
          u3, nodes_c, nullptr, nullptr, zv, rf, hvp, nullptr);
      float* outf = (step == 2) ? outF_c : nullptr;
      gemm_nt<EPI_G4><<<g_d, 256, 0, stream>>>(
          rf, D_, w5ub, nullptr, nullptr, D_, D_, b5u, nullptr, nullptr,
          nullptr, nodes_c, hvp, zv, nodes_c, nullptr, nullptr, outf);
    }
  }
}

// Round 11
// 789.470 us; speedup vs baseline: 1.0166x; 1.0166x over previous
//
#include <hip/hip_runtime.h>
#include <cstdint>
#include <cstddef>

// GNN (GGNN) on MI355X. Inputs fp32, output fp32; internal bf16 MFMA w/ fp32
// accum (passing since round 6: absmax 0.0117 vs threshold 0.028).
// ROUND 11: revert round-10 av2 pairing (regressed; untouched BIG slowed 25%
// with identical counters -> env/noise suspicion, av2 gave no net win).
// Back to R9-verified pipeline + ONE change: single-barrier double-buffered
// global_load_lds staging: barrier(drain prev DMA) -> issue DMA(k+1, other
// buf) -> compute(buf k). DMA now overlaps MFMA within a block; barrier
// count halved (was 2/iter with a full vmcnt(0) drain between issue and use).
// Retained: BK=32 (R8: BK=64 occupancy cliff), conflict-free chunk swizzle
// (R9: conflicts 6.29M->0), XCD banding (R8: FETCH 162->72MB), DMA w16 (R7),
// fused converts, fast sigmoid/tanh.
// Per step: T=nodes^T; av=[inM@nodes | outM@nodes]; u3=nodes@w3u^T+b3u;
// [z|r|h]pre=av@[w3w|w4w|w5w]^T (epilogue: gates, rf=r*nodes);
// t=rf@w5u^T; nodes=(1-z)*nodes+z*tanh(hpre+t+b5u).
// Output: nodes (fp32) ++ in_matrix (fp32 passthrough).

#define B_ 16
#define N_ 1024
#define D_ 512
#define S_ (B_ * N_)      // 16384
#define TWO_D 1024

typedef __attribute__((ext_vector_type(8))) short short8;
typedef __attribute__((ext_vector_type(4))) short s16x4;
typedef __attribute__((ext_vector_type(4))) float f32x4;

#define EPI_AV  0
#define EPI_U3  1
#define EPI_BIG 2
#define EPI_G4  3

__device__ __forceinline__ float bf2f(short u) {
  union { unsigned int i; float f; } v;
  v.i = ((unsigned int)(unsigned short)u) << 16;
  return v.f;
}
__device__ __forceinline__ short f2bf(float f) {
  union { float f; unsigned int i; } v;
  v.f = f;
  unsigned int x = v.i;
  unsigned int r = (x + 0x7fffu + ((x >> 16) & 1u)) >> 16;  // RTNE
  return (short)(unsigned short)r;
}
__device__ __forceinline__ float fast_sigmoid(float x) {
  return __builtin_amdgcn_rcpf(1.f + __expf(-x));
}
__device__ __forceinline__ float fast_tanh(float x) {
  const float t = __expf(-2.f * fabsf(x));
  const float th = (1.f - t) * __builtin_amdgcn_rcpf(1.f + t);
  return __builtin_copysignf(th, x);
}

// Async global->LDS DMA, 16 bytes/lane; LDS dest = wave-uniform base+lane*16.
__device__ __forceinline__ void gload16(const void* g, void* l) {
  __builtin_amdgcn_global_load_lds(
      (__attribute__((address_space(1))) void*)g,
      (__attribute__((address_space(3))) void*)l, 16, 0, 0);
}

// C[M,Nc] = A[M,K] * Bw[Nc,K]^T, bf16 in memory, fp32 accum.
// 128x128 tile, BK=32, 256 threads = 4 waves (2x2), wave 64x64 via 4x4
// mfma_f32_16x16x32_bf16. Verified layouts (m89/m91):
//   A/B frag: row/col = lane&15, k = (lane>>4)*8 + j
//   C/D:      col = lane&15, row = (lane>>4)*4 + r
// LDS chunk swizzle: row-slot r stores global k-chunk q at position
// (q + (r>>1)) & 3 -> conflict-free ds_read_b128, DMA-legal lane-linear dest.
// Double-buffered: DMA for slab k+1 issued after the barrier that publishes
// slab k, overlapping with slab k's MFMAs.
template <int EPI>
__global__ __launch_bounds__(256) void gemm_nt(
    const short* A, const short* A2, int lda,
    const short* Bw, const short* Bw2, const short* Bw3, int ldb, int K,
    const float* bias0, const float* bias1, const float* bias2,
    const short* u3, const short* fcur,   // may alias out0 (in-place G4)
    const short* hvp, const short* zvp,
    short* out0, short* out1, short* out2,
    float* outf) {                         // EPI_G4 final step: fp32 d_out
  __shared__ __align__(16) short lds_a[2 * 128 * 32];   // 2 x 8 KB
  __shared__ __align__(16) short lds_b[2 * 128 * 32];   // 2 x 8 KB

  const int tid = threadIdx.x;
  const int lane = tid & 63;
  const int wave = tid >> 6;
  const int wr = wave >> 1, wc = wave & 1;

  // ---- XCD-aware swizzle (assumes linear-block -> XCD = id % 8) ----
  int bx = blockIdx.x, by = blockIdx.y, bz = blockIdx.z;
  if constexpr (EPI == EPI_AV) {
    if (gridDim.z == 32) {   // full-batch case: 4 z-slices per XCD
      const int id = (bz * gridDim.y + by) * gridDim.x + bx;  // gx=4, gy=8
      const int a = id & 7, b = (id >> 3) & 3, c = id >> 5;
      bz = a * 4 + b;
      by = c >> 2;
      bx = c & 3;
    }
  } else {
    // y divisible by 8: give each XCD a contiguous y-band (A-row reuse)
    const int gx = gridDim.x, gy = gridDim.y;
    if ((gy & 7) == 0) {
      const int id = by * gx + bx;
      const int a = id & 7;
      const int m = id >> 3;
      const int per = gy >> 3;
      by = a * per + m / gx;
      bx = m % gx;
    }
  }

  const int m0 = by * 128;
  const int n0 = bx * 128;

  const short* Aeff = A;
  const short* Beff = Bw;
  int nb0 = n0;
  int b_ = 0, j_ = 0;
  if constexpr (EPI == EPI_AV) {
    b_ = bz >> 1;
    j_ = bz & 1;
    Aeff = j_ ? A2 : A;                              // inM / outM
    Beff = Bw + (size_t)b_ * ((size_t)D_ * N_);      // T for batch b_
  } else if constexpr (EPI == EPI_BIG) {
    if (n0 < 512) { Beff = Bw; nb0 = n0; }
    else if (n0 < 1024) { Beff = Bw2; nb0 = n0 - 512; }
    else { Beff = Bw3; nb0 = n0 - 1024; }
  }

  f32x4 acc[4][4];
#pragma unroll
  for (int i = 0; i < 4; i++)
#pragma unroll
    for (int j = 0; j < 4; j++) acc[i][j] = (f32x4){0.f, 0.f, 0.f, 0.f};

  const int ar = tid >> 2;                    // row-slot 0..63
  const int sc = tid & 3;                     // stored chunk position
  const int qg = (sc - (ar >> 1)) & 3;        // global k-chunk (conflict-free)
  const int ac = qg * 8;
  char* la = (char*)lds_a + tid * 16;
  char* lb = (char*)lds_b + tid * 16;
  const short* ga0 = Aeff + (size_t)(m0 + ar) * lda + ac;
  const short* ga1 = Aeff + (size_t)(m0 + ar + 64) * lda + ac;
  const short* gb0 = Beff + (size_t)(nb0 + ar) * ldb + ac;
  const short* gb1 = Beff + (size_t)(nb0 + ar + 64) * ldb + ac;

  const int lm = lane & 15;
  const int qq = lane >> 4;

  // prologue: DMA slab 0 into buffer 0
  gload16(ga0, la);
  gload16(ga1, la + 4096);
  gload16(gb0, lb);
  gload16(gb1, lb + 4096);

  const int niter = K / 32;
  for (int it = 0; it < niter; ++it) {
    __syncthreads();   // drains DMA(it) [compiler emits vmcnt(0) here]
    // prefetch slab it+1 into the other buffer; overlaps with MFMAs below
    if (it + 1 < niter) {
      const int kn = (it + 1) * 32;
      const int bo = ((it + 1) & 1) * 8192;
      gload16(ga0 + kn, la + bo);
      gload16(ga1 + kn, la + bo + 4096);
      gload16(gb0 + kn, lb + bo);
      gload16(gb1 + kn, lb + bo + 4096);
    }
    const int cb = (it & 1) * 8192;  // compute buffer byte offset

    short8 af[4], bfr[4];
#pragma unroll
    for (int i = 0; i < 4; i++) {
      const int Ra = wr * 64 + i * 16 + lm;
      af[i] = *(const short8*)((const char*)lds_a + cb + Ra * 64 +
                               (((qq + (Ra >> 1)) & 3) << 4));
    }
#pragma unroll
    for (int j = 0; j < 4; j++) {
      const int Rb = wc * 64 + j * 16 + lm;
      bfr[j] = *(const short8*)((const char*)lds_b + cb + Rb * 64 +
                                (((qq + (Rb >> 1)) & 3) << 4));
    }
#pragma unroll
    for (int i = 0; i < 4; i++)
#pragma unroll
      for (int j = 0; j < 4; j++)
        acc[i][j] = __builtin_amdgcn_mfma_f32_16x16x32_bf16(
            af[i], bfr[j], acc[i][j], 0, 0, 0);
  }

  const int r0 = (lane >> 4) * 4;
#pragma unroll
  for (int i = 0; i < 4; i++) {
#pragma unroll
    for (int j = 0; j < 4; j++) {
#pragma unroll
      for (int r = 0; r < 4; r++) {
        const int grow = m0 + wr * 64 + i * 16 + r0 + r;
        const int gcol = n0 + wc * 64 + j * 16 + lm;
        const float v = acc[i][j][r];
        if constexpr (EPI == EPI_AV) {
          out0[((size_t)(b_ * N_ + grow)) * TWO_D + j_ * D_ + gcol] = f2bf(v);
        } else if constexpr (EPI == EPI_U3) {
          out0[(size_t)grow * D_ + gcol] = f2bf(v + bias0[gcol]);
        } else if constexpr (EPI == EPI_BIG) {
          if (gcol < 512) {
            const size_t sidx = (size_t)grow * D_ + gcol;
            const float x = v + bias0[gcol] + bf2f(u3[sidx]);
            out0[sidx] = f2bf(fast_sigmoid(x));
          } else if (gcol < 1024) {
            const int e = gcol - 512;
            const size_t sidx = (size_t)grow * D_ + e;
            const float x = v + bias1[e] + bf2f(u3[sidx]);
            out1[sidx] = f2bf(fast_sigmoid(x) * bf2f(fcur[sidx]));
          } else {
            const int e = gcol - 1024;
            const size_t sidx = (size_t)grow * D_ + e;
            out2[sidx] = f2bf(v + bias2[e]);
          }
        } else {  // EPI_G4 (in-place: same thread reads then writes sidx)
          const size_t sidx = (size_t)grow * D_ + gcol;
          const float x = bf2f(hvp[sidx]) + v + bias0[gcol];
          const float hv = fast_tanh(x);
          const float z = bf2f(zvp[sidx]);
          const float f = bf2f(fcur[sidx]);
          const float res = (1.f - z) * f + z * hv;
          if (outf) outf[sidx] = res;      // final step: fp32 to d_out
          else out0[sidx] = f2bf(res);     // intermediate: bf16 nodes update
        }
      }
    }
  }
}

// bf16 [C][N][D] -> bf16 [C][D][N] transpose.
__global__ void transpose_bnd(const short* __restrict__ in,
                              short* __restrict__ out) {
  __shared__ short tile[32][33];
  const int b = blockIdx.z;
  const int n0 = blockIdx.y * 32;
  const int d0 = blockIdx.x * 32;
  const int tx = threadIdx.x, ty = threadIdx.y;
  const short* ip = in + (size_t)b * N_ * D_;
  short* op = out + (size_t)b * N_ * D_;
#pragma unroll
  for (int yy = ty; yy < 32; yy += 8)
    tile[yy][tx] = ip[(size_t)(n0 + yy) * D_ + d0 + tx];
  __syncthreads();
#pragma unroll
  for (int yy = ty; yy < 32; yy += 8)
    op[(size_t)(d0 + yy) * N_ + n0 + tx] = tile[tx][yy];
}

// One-shot segmented fp32->bf16 convert (8 jobs, grid-stride over v4 elems).
struct CvtJobs {
  const float* src[8];
  short* dst[8];
  int end4[8];
  int tot4;
};
__global__ void cvt_all(CvtJobs j) {
  for (int idx = blockIdx.x * 256 + threadIdx.x; idx < j.tot4;
       idx += gridDim.x * 256) {
    int k = 0, start = 0;
#pragma unroll
    for (int t = 0; t < 8; t++) {
      if (idx >= j.end4[t]) { k = t + 1; start = j.end4[t]; }
    }
    const int rel = idx - start;
    const f32x4 v = ((const f32x4*)j.src[k])[rel];
    s16x4 o;
#pragma unroll
    for (int r = 0; r < 4; r++) o[r] = f2bf(v[r]);
    ((s16x4*)j.dst[k])[rel] = o;
  }
}

extern "C" void kernel_launch(void* const* d_in, const int* in_sizes, int n_in,
                              void* d_out, int out_size, void* d_ws,
                              size_t ws_size, hipStream_t stream) {
  const float* x = (const float*)d_in[0];
  const float* inM = (const float*)d_in[1];
  const float* outM = (const float*)d_in[2];
  const float* w3w = (const float*)d_in[3];
  const float* b3w = (const float*)d_in[4];
  const float* w3u = (const float*)d_in[5];
  const float* b3u = (const float*)d_in[6];
  const float* w4w = (const float*)d_in[7];
  const float* b4w = (const float*)d_in[8];
  const float* w5w = (const float*)d_in[9];
  const float* b5w = (const float*)d_in[10];
  const float* w5u = (const float*)d_in[11];
  const float* b5u = (const float*)d_in[12];
  float* outF = (float*)d_out;   // fp32 output: nodes [S_,D_] ++ in_matrix

  char* ws = (char*)d_ws;
  size_t off = 0;
  auto alloc = [&](size_t elems) {
    short* p = (short*)(ws + off);
    off = (off + elems * 2 + 255) & ~(size_t)255;
    return p;
  };
  short* nodes = alloc((size_t)S_ * D_);           // bf16 recursion state
  short* inMb = alloc((size_t)N_ * N_);
  short* outMb = alloc((size_t)N_ * N_);
  short* w3wb = alloc((size_t)512 * 1024);
  short* w4wb = alloc((size_t)512 * 1024);
  short* w5wb = alloc((size_t)512 * 1024);
  short* w3ub = alloc((size_t)D_ * D_);
  short* w5ub = alloc((size_t)D_ * D_);
  const size_t fixed = off;

  // chunk size C: per-chunk scratch = T+av+u3+zv+rf+hvp = 7*C*N*D bf16
  int C = 1;
  for (int c = 16; c >= 1; c >>= 1) {
    const size_t need = fixed + (size_t)7 * c * N_ * D_ * 2 + 8 * 256;
    if (need <= ws_size) { C = c; break; }
  }
  short* T = alloc((size_t)C * D_ * N_);
  short* av = alloc((size_t)C * N_ * TWO_D);
  short* u3 = alloc((size_t)C * N_ * D_);
  short* zv = alloc((size_t)C * N_ * D_);
  short* rf = alloc((size_t)C * N_ * D_);
  short* hvp = alloc((size_t)C * N_ * D_);

  // --- one fused convert launch: fp32 -> bf16 working set ---
  CvtJobs cj;
  const int xs4 = S_ * D_ / 4, nn4 = N_ * N_ / 4;
  const int dd4 = D_ * D_ / 4, wd4 = 512 * 1024 / 4;
  const float* srcs[8] = {x, inM, outM, w3w, w4w, w5w, w3u, w5u};
  short* dsts[8] = {nodes, inMb, outMb, w3wb, w4wb, w5wb, w3ub, w5ub};
  const int lens[8] = {xs4, nn4, nn4, wd4, wd4, wd4, dd4, dd4};
  int cum = 0;
  for (int i = 0; i < 8; i++) {
    cj.src[i] = srcs[i];
    cj.dst[i] = dsts[i];
    cum += lens[i];
    cj.end4[i] = cum;
  }
  cj.tot4 = cum;
  cvt_all<<<1536, 256, 0, stream>>>(cj);
  // output 1: in_matrix passthrough (fp32 bit copy)
  hipMemcpyAsync(outF + (size_t)S_ * D_, inM, (size_t)N_ * N_ * 4,
                 hipMemcpyDeviceToDevice, stream);

  const dim3 tb32(32, 8);
  const dim3 tg(D_ / 32, N_ / 32, C);
  const dim3 g_adj(D_ / 128, N_ / 128, 2 * C);
  const dim3 g_d(D_ / 128, C * N_ / 128, 1);
  const dim3 g_big(1536 / 128, C * N_ / 128, 1);

  const int nchunks = B_ / C;
  for (int c = 0; c < nchunks; ++c) {
    short* nodes_c = nodes + (size_t)c * C * N_ * D_;
    float* outF_c = outF + (size_t)c * C * N_ * D_;
    for (int step = 0; step < 3; ++step) {
      transpose_bnd<<<tg, tb32, 0, stream>>>(nodes_c, T);
      gemm_nt<EPI_AV><<<g_adj, 256, 0, stream>>>(
          inMb, outMb, N_, T, nullptr, nullptr, N_, N_, nullptr, nullptr,
          nullptr, nullptr, nullptr, nullptr, nullptr, av, nullptr, nullptr,
          nullptr);
      gemm_nt<EPI_U3><<<g_d, 256, 0, stream>>>(
          nodes_c, nullptr, D_, w3ub, nullptr, nullptr, D_, D_, b3u, nullptr,
          nullptr, nullptr, nullptr, nullptr, nullptr, u3, nullptr, nullptr,
          nullptr);
      gemm_nt<EPI_BIG><<<g_big, 256, 0, stream>>>(
          av, nullptr, TWO_D, w3wb, w4wb, w5wb, TWO_D, TWO_D, b3w, b4w, b5w,
          u3, nodes_c, nullptr, nullptr, zv, rf, hvp, nullptr);
      float* outf = (step == 2) ? outF_c : nullptr;
      gemm_nt<EPI_G4><<<g_d, 256, 0, stream>>>(
          rf, nullptr, D_, w5ub, nullptr, nullptr, D_, D_, b5u, nullptr,
          nullptr, nullptr, nodes_c, hvp, zv, nodes_c, nullptr, nullptr,
          outf);
    }
  }
}

// Round 12
// 771.926 us; speedup vs baseline: 1.0397x; 1.0227x over previous
//
#include <hip/hip_runtime.h>
#include <cstdint>
#include <cstddef>

// GNN (GGNN) on MI355X. Inputs fp32, output fp32; internal bf16 MFMA w/ fp32
// accum (passing since round 6: absmax 0.0117 vs threshold 0.028).
// ROUND 12: revert R11 dbuf (LDS 32KB cut occupancy 29->20%, BIG 109->129us;
// within-block overlap < lost cross-block TLP). Back to R9 core (BK=32,
// single buffer, 2 barriers, 16KB LDS) plus:
//  (1) AV+U3 merged into ONE dispatch (independent GEMMs; grid z: [0,2C)=AV,
//      [2C,3C)=U3) -> one less serialization/step, U3 tail packed.
//  (2) LDS frag offsets hoisted out of the K-loop (loop-invariant).
// Retained: conflict-free chunk swizzle (R9: conflicts 6.29M->0), XCD
// banding (R8: FETCH 162->72MB), global_load_lds w16 (R7), fused converts,
// fast sigmoid/tanh.
// Per step: T=nodes^T; [av | u3] fused dispatch; BIG: [z|r|h]pre=
// av@[w3w|w4w|w5w]^T (gates, rf=r*nodes); G4: t=rf@w5u^T;
// nodes=(1-z)*nodes+z*tanh(hpre+t+b5u).
// Output: nodes (fp32) ++ in_matrix (fp32 passthrough).

#define B_ 16
#define N_ 1024
#define D_ 512
#define S_ (B_ * N_)      // 16384
#define TWO_D 1024

typedef __attribute__((ext_vector_type(8))) short short8;
typedef __attribute__((ext_vector_type(4))) short s16x4;
typedef __attribute__((ext_vector_type(4))) float f32x4;

#define EPI_AVU3 0
#define EPI_BIG  2
#define EPI_G4   3

__device__ __forceinline__ float bf2f(short u) {
  union { unsigned int i; float f; } v;
  v.i = ((unsigned int)(unsigned short)u) << 16;
  return v.f;
}
__device__ __forceinline__ short f2bf(float f) {
  union { float f; unsigned int i; } v;
  v.f = f;
  unsigned int x = v.i;
  unsigned int r = (x + 0x7fffu + ((x >> 16) & 1u)) >> 16;  // RTNE
  return (short)(unsigned short)r;
}
__device__ __forceinline__ float fast_sigmoid(float x) {
  return __builtin_amdgcn_rcpf(1.f + __expf(-x));
}
__device__ __forceinline__ float fast_tanh(float x) {
  const float t = __expf(-2.f * fabsf(x));
  const float th = (1.f - t) * __builtin_amdgcn_rcpf(1.f + t);
  return __builtin_copysignf(th, x);
}

// Async global->LDS DMA, 16 bytes/lane; LDS dest = wave-uniform base+lane*16.
__device__ __forceinline__ void gload16(const void* g, void* l) {
  __builtin_amdgcn_global_load_lds(
      (__attribute__((address_space(1))) void*)g,
      (__attribute__((address_space(3))) void*)l, 16, 0, 0);
}

// C[M,Nc] = A[M,K] * Bw[Nc,K]^T, bf16 in memory, fp32 accum.
// 128x128 tile, BK=32, 256 threads = 4 waves (2x2), wave 64x64 via 4x4
// mfma_f32_16x16x32_bf16. Verified layouts (m89/m91):
//   A/B frag: row/col = lane&15, k = (lane>>4)*8 + j
//   C/D:      col = lane&15, row = (lane>>4)*4 + r
// LDS chunk swizzle: row-slot r stores global k-chunk q at position
// (q + (r>>1)) & 3 -> conflict-free ds_read_b128, DMA-legal lane-linear dest.
// EPI_AVU3: blockIdx.z < 2C -> adjacency GEMM slice (batch z>>1, inM/outM by
// z&1, K=N_); z >= 2C -> U3 GEMM for batch z-2C (K=D_).
template <int EPI>
__global__ __launch_bounds__(256) void gemm_nt(
    const short* A, const short* A2, int lda,
    const short* Bw, const short* Bw2, const short* Bw3, int ldb, int Kin,
    const float* bias0, const float* bias1, const float* bias2,
    const short* u3, const short* fcur,   // may alias out0 (in-place G4)
    const short* hvp, const short* zvp,
    short* out0, short* out1, short* out2,
    float* outf, int twoC) {               // EPI_G4 final step: fp32 d_out
  __shared__ __align__(16) short lds_a[128 * 32];   // 8 KB
  __shared__ __align__(16) short lds_b[128 * 32];   // 8 KB

  const int tid = threadIdx.x;
  const int lane = tid & 63;
  const int wave = tid >> 6;
  const int wr = wave >> 1, wc = wave & 1;

  // ---- XCD-aware swizzle (assumes linear-block -> XCD = id % 8) ----
  int bx = blockIdx.x, by = blockIdx.y, bz = blockIdx.z;
  if constexpr (EPI == EPI_AVU3) {
    // swizzle over the full 3D grid: contiguous id-chunks per XCD
    const int total = gridDim.x * gridDim.y * gridDim.z;
    const int id = (bz * gridDim.y + by) * gridDim.x + bx;
    if ((total & 7) == 0) {
      const int a = id & 7, m = id >> 3;
      const int l = a * (total >> 3) + m;
      bx = l & 3;                 // gx = 4
      by = (l >> 2) & 7;          // gy = 8
      bz = l >> 5;
    }
  } else {
    // y divisible by 8: give each XCD a contiguous y-band (A-row reuse)
    const int gx = gridDim.x, gy = gridDim.y;
    if ((gy & 7) == 0) {
      const int id = by * gx + bx;
      const int a = id & 7;
      const int m = id >> 3;
      const int per = gy >> 3;
      by = a * per + m / gx;
      bx = m % gx;
    }
  }

  int m0 = by * 128;
  const int n0 = bx * 128;
  int K = Kin;

  const short* Aeff = A;
  const short* Beff = Bw;
  int lda_e = lda, ldb_e = ldb;
  int nb0 = n0;
  bool isU3 = false;
  int b_ = 0, j_ = 0;
  if constexpr (EPI == EPI_AVU3) {
    if (bz < twoC) {               // adjacency slice
      b_ = bz >> 1;
      j_ = bz & 1;
      Aeff = j_ ? A2 : A;                              // inM / outM (lda=N_)
      Beff = Bw + (size_t)b_ * ((size_t)D_ * N_);      // T for batch b_
      lda_e = N_; ldb_e = N_; K = N_;
    } else {                       // U3 slice for batch bz-twoC
      isU3 = true;
      const int b = bz - twoC;
      Aeff = u3 /*nodes*/ + (size_t)b * N_ * D_;       // nodes rows
      m0 = by * 128;               // local row tile within batch
      Beff = Bw3 /*w3u*/;
      lda_e = D_; ldb_e = D_; K = D_;
      b_ = b;
    }
  } else if constexpr (EPI == EPI_BIG) {
    if (n0 < 512) { Beff = Bw; nb0 = n0; }
    else if (n0 < 1024) { Beff = Bw2; nb0 = n0 - 512; }
    else { Beff = Bw3; nb0 = n0 - 1024; }
  }

  f32x4 acc[4][4];
#pragma unroll
  for (int i = 0; i < 4; i++)
#pragma unroll
    for (int j = 0; j < 4; j++) acc[i][j] = (f32x4){0.f, 0.f, 0.f, 0.f};

  const int ar = tid >> 2;                    // row-slot 0..63
  const int sc = tid & 3;                     // stored chunk position
  const int qg = (sc - (ar >> 1)) & 3;        // global k-chunk (conflict-free)
  const int ac = qg * 8;
  char* la = (char*)lds_a + tid * 16;
  char* lb = (char*)lds_b + tid * 16;
  const short* ga0 = Aeff + (size_t)(m0 + ar) * lda_e + ac;
  const short* ga1 = Aeff + (size_t)(m0 + ar + 64) * lda_e + ac;
  const short* gb0 = Beff + (size_t)(nb0 + ar) * ldb_e + ac;
  const short* gb1 = Beff + (size_t)(nb0 + ar + 64) * ldb_e + ac;

  const int lm = lane & 15;
  const int qq = lane >> 4;

  // hoisted loop-invariant LDS frag byte offsets
  int offA[4], offB[4];
#pragma unroll
  for (int i = 0; i < 4; i++) {
    const int Ra = wr * 64 + i * 16 + lm;
    offA[i] = Ra * 64 + (((qq + (Ra >> 1)) & 3) << 4);
    const int Rb = wc * 64 + i * 16 + lm;
    offB[i] = Rb * 64 + (((qq + (Rb >> 1)) & 3) << 4);
  }

  for (int k0 = 0; k0 < K; k0 += 32) {
    __syncthreads();
    gload16(ga0 + k0, la);
    gload16(ga1 + k0, la + 4096);
    gload16(gb0 + k0, lb);
    gload16(gb1 + k0, lb + 4096);
    __syncthreads();

    short8 af[4], bfr[4];
#pragma unroll
    for (int i = 0; i < 4; i++) {
      af[i] = *(const short8*)((const char*)lds_a + offA[i]);
      bfr[i] = *(const short8*)((const char*)lds_b + offB[i]);
    }
#pragma unroll
    for (int i = 0; i < 4; i++)
#pragma unroll
      for (int j = 0; j < 4; j++)
        acc[i][j] = __builtin_amdgcn_mfma_f32_16x16x32_bf16(
            af[i], bfr[j], acc[i][j], 0, 0, 0);
  }

  const int r0 = (lane >> 4) * 4;
#pragma unroll
  for (int i = 0; i < 4; i++) {
#pragma unroll
    for (int j = 0; j < 4; j++) {
#pragma unroll
      for (int r = 0; r < 4; r++) {
        const int grow = m0 + wr * 64 + i * 16 + r0 + r;
        const int gcol = n0 + wc * 64 + j * 16 + lm;
        const float v = acc[i][j][r];
        if constexpr (EPI == EPI_AVU3) {
          if (!isU3) {
            out0[((size_t)(b_ * N_ + grow)) * TWO_D + j_ * D_ + gcol] =
                f2bf(v);
          } else {
            out1[((size_t)(b_ * N_ + grow)) * D_ + gcol] =
                f2bf(v + bias0[gcol]);
          }
        } else if constexpr (EPI == EPI_BIG) {
          if (gcol < 512) {
            const size_t sidx = (size_t)grow * D_ + gcol;
            const float x = v + bias0[gcol] + bf2f(u3[sidx]);
            out0[sidx] = f2bf(fast_sigmoid(x));
          } else if (gcol < 1024) {
            const int e = gcol - 512;
            const size_t sidx = (size_t)grow * D_ + e;
            const float x = v + bias1[e] + bf2f(u3[sidx]);
            out1[sidx] = f2bf(fast_sigmoid(x) * bf2f(fcur[sidx]));
          } else {
            const int e = gcol - 1024;
            const size_t sidx = (size_t)grow * D_ + e;
            out2[sidx] = f2bf(v + bias2[e]);
          }
        } else {  // EPI_G4 (in-place: same thread reads then writes sidx)
          const size_t sidx = (size_t)grow * D_ + gcol;
          const float x = bf2f(hvp[sidx]) + v + bias0[gcol];
          const float hv = fast_tanh(x);
          const float z = bf2f(zvp[sidx]);
          const float f = bf2f(fcur[sidx]);
          const float res = (1.f - z) * f + z * hv;
          if (outf) outf[sidx] = res;      // final step: fp32 to d_out
          else out0[sidx] = f2bf(res);     // intermediate: bf16 nodes update
        }
      }
    }
  }
}

// bf16 [C][N][D] -> bf16 [C][D][N] transpose.
__global__ void transpose_bnd(const short* __restrict__ in,
                              short* __restrict__ out) {
  __shared__ short tile[32][33];
  const int b = blockIdx.z;
  const int n0 = blockIdx.y * 32;
  const int d0 = blockIdx.x * 32;
  const int tx = threadIdx.x, ty = threadIdx.y;
  const short* ip = in + (size_t)b * N_ * D_;
  short* op = out + (size_t)b * N_ * D_;
#pragma unroll
  for (int yy = ty; yy < 32; yy += 8)
    tile[yy][tx] = ip[(size_t)(n0 + yy) * D_ + d0 + tx];
  __syncthreads();
#pragma unroll
  for (int yy = ty; yy < 32; yy += 8)
    op[(size_t)(d0 + yy) * N_ + n0 + tx] = tile[tx][yy];
}

// One-shot segmented fp32->bf16 convert (8 jobs, grid-stride over v4 elems).
struct CvtJobs {
  const float* src[8];
  short* dst[8];
  int end4[8];
  int tot4;
};
__global__ void cvt_all(CvtJobs j) {
  for (int idx = blockIdx.x * 256 + threadIdx.x; idx < j.tot4;
       idx += gridDim.x * 256) {
    int k = 0, start = 0;
#pragma unroll
    for (int t = 0; t < 8; t++) {
      if (idx >= j.end4[t]) { k = t + 1; start = j.end4[t]; }
    }
    const int rel = idx - start;
    const f32x4 v = ((const f32x4*)j.src[k])[rel];
    s16x4 o;
#pragma unroll
    for (int r = 0; r < 4; r++) o[r] = f2bf(v[r]);
    ((s16x4*)j.dst[k])[rel] = o;
  }
}

extern "C" void kernel_launch(void* const* d_in, const int* in_sizes, int n_in,
                              void* d_out, int out_size, void* d_ws,
                              size_t ws_size, hipStream_t stream) {
  const float* x = (const float*)d_in[0];
  const float* inM = (const float*)d_in[1];
  const float* outM = (const float*)d_in[2];
  const float* w3w = (const float*)d_in[3];
  const float* b3w = (const float*)d_in[4];
  const float* w3u = (const float*)d_in[5];
  const float* b3u = (const float*)d_in[6];
  const float* w4w = (const float*)d_in[7];
  const float* b4w = (const float*)d_in[8];
  const float* w5w = (const float*)d_in[9];
  const float* b5w = (const float*)d_in[10];
  const float* w5u = (const float*)d_in[11];
  const float* b5u = (const float*)d_in[12];
  float* outF = (float*)d_out;   // fp32 output: nodes [S_,D_] ++ in_matrix

  char* ws = (char*)d_ws;
  size_t off = 0;
  auto alloc = [&](size_t elems) {
    short* p = (short*)(ws + off);
    off = (off + elems * 2 + 255) & ~(size_t)255;
    return p;
  };
  short* nodes = alloc((size_t)S_ * D_);           // bf16 recursion state
  short* inMb = alloc((size_t)N_ * N_);
  short* outMb = alloc((size_t)N_ * N_);
  short* w3wb = alloc((size_t)512 * 1024);
  short* w4wb = alloc((size_t)512 * 1024);
  short* w5wb = alloc((size_t)512 * 1024);
  short* w3ub = alloc((size_t)D_ * D_);
  short* w5ub = alloc((size_t)D_ * D_);
  const size_t fixed = off;

  // chunk size C: per-chunk scratch = T+av+u3+zv+rf+hvp = 7*C*N*D bf16
  int C = 1;
  for (int c = 16; c >= 1; c >>= 1) {
    const size_t need = fixed + (size_t)7 * c * N_ * D_ * 2 + 8 * 256;
    if (need <= ws_size) { C = c; break; }
  }
  short* T = alloc((size_t)C * D_ * N_);
  short* av = alloc((size_t)C * N_ * TWO_D);
  short* u3 = alloc((size_t)C * N_ * D_);
  short* zv = alloc((size_t)C * N_ * D_);
  short* rf = alloc((size_t)C * N_ * D_);
  short* hvp = alloc((size_t)C * N_ * D_);

  // --- one fused convert launch: fp32 -> bf16 working set ---
  CvtJobs cj;
  const int xs4 = S_ * D_ / 4, nn4 = N_ * N_ / 4;
  const int dd4 = D_ * D_ / 4, wd4 = 512 * 1024 / 4;
  const float* srcs[8] = {x, inM, outM, w3w, w4w, w5w, w3u, w5u};
  short* dsts[8] = {nodes, inMb, outMb, w3wb, w4wb, w5wb, w3ub, w5ub};
  const int lens[8] = {xs4, nn4, nn4, wd4, wd4, wd4, dd4, dd4};
  int cum = 0;
  for (int i = 0; i < 8; i++) {
    cj.src[i] = srcs[i];
    cj.dst[i] = dsts[i];
    cum += lens[i];
    cj.end4[i] = cum;
  }
  cj.tot4 = cum;
  cvt_all<<<1536, 256, 0, stream>>>(cj);
  // output 1: in_matrix passthrough (fp32 bit copy)
  hipMemcpyAsync(outF + (size_t)S_ * D_, inM, (size_t)N_ * N_ * 4,
                 hipMemcpyDeviceToDevice, stream);

  const dim3 tb32(32, 8);
  const dim3 tg(D_ / 32, N_ / 32, C);
  const dim3 g_avu3(D_ / 128, N_ / 128, 3 * C);   // AV (2C) + U3 (C)
  const dim3 g_d(D_ / 128, C * N_ / 128, 1);
  const dim3 g_big(1536 / 128, C * N_ / 128, 1);

  const int nchunks = B_ / C;
  for (int c = 0; c < nchunks; ++c) {
    short* nodes_c = nodes + (size_t)c * C * N_ * D_;
    float* outF_c = outF + (size_t)c * C * N_ * D_;
    for (int step = 0; step < 3; ++step) {
      transpose_bnd<<<tg, tb32, 0, stream>>>(nodes_c, T);
      // fused AV + U3: AV uses (A=inMb, A2=outMb, Bw=T); U3 uses
      // (u3-slot = nodes base [A for U3], Bw3 = w3u); out0=av, out1=u3.
      gemm_nt<EPI_AVU3><<<g_avu3, 256, 0, stream>>>(
          inMb, outMb, N_, T, nullptr, w3ub, N_, N_, b3u, nullptr, nullptr,
          nodes_c, nullptr, nullptr, nullptr, av, u3, nullptr, nullptr,
          2 * C);
      gemm_nt<EPI_BIG><<<g_big, 256, 0, stream>>>(
          av, nullptr, TWO_D, w3wb, w4wb, w5wb, TWO_D, TWO_D, b3w, b4w, b5w,
          u3, nodes_c, nullptr, nullptr, zv, rf, hvp, nullptr, 0);
      float* outf = (step == 2) ? outF_c : nullptr;
      gemm_nt<EPI_G4><<<g_d, 256, 0, stream>>>(
          rf, nullptr, D_, w5ub, nullptr, nullptr, D_, D_, b5u, nullptr,
          nullptr, nullptr, nodes_c, hvp, zv, nodes_c, nullptr, nullptr,
          outf, 0);
    }
  }
}

// Round 13
// 662.735 us; speedup vs baseline: 1.2110x; 1.1648x over previous
//
#include <hip/hip_runtime.h>
#include <cstdint>
#include <cstddef>

// GNN (GGNN) on MI355X. Inputs fp32, output fp32; internal bf16 MFMA w/ fp32
// accum (passing since round 6: absmax 0.0117 vs threshold 0.028).
// ROUND 13: occupancy retile. All pipes <40% + occ 28.6% (9.2 waves/CU) =
// latency-bound (roofline table row 3). Same 128x128x32 tile but 8 waves of
// 64x32 (512 thr): acc 64->32 AGPR/wave, frags 32->24 VGPR -> ~107 total,
// __launch_bounds__(512,4) caps 128 -> 4 waves/SIMD = 16 waves/CU (1.7x
// latency hiding). DMA = 2 gload16/thread (tid*16 spans full 8KB panel,
// lane-linear contract intact); conflict-free chunk swizzle unchanged.
// Known cost: LDS reads/iter 48->64KB (counters say LDS BW not binding).
// Retained: BK=32 single-buffer 2-barrier loop (R11 dbuf regressed), XCD
// banding (R8), DMA w16 (R7), conflict-free swizzle (R9: 6.29M->0), merged
// AVU3 dispatch (R12), fused converts, fast sigmoid/tanh.
// Per step: T=nodes^T; [av|u3] fused; BIG: [z|r|h]pre=av@[w3w|w4w|w5w]^T
// (gates, rf=r*nodes); G4: t=rf@w5u^T; nodes=(1-z)*nodes+z*tanh(hpre+t+b5u).
// Output: nodes (fp32) ++ in_matrix (fp32 passthrough).

#define B_ 16
#define N_ 1024
#define D_ 512
#define S_ (B_ * N_)      // 16384
#define TWO_D 1024

typedef __attribute__((ext_vector_type(8))) short short8;
typedef __attribute__((ext_vector_type(4))) short s16x4;
typedef __attribute__((ext_vector_type(4))) float f32x4;

#define EPI_AVU3 0
#define EPI_BIG  2
#define EPI_G4   3

__device__ __forceinline__ float bf2f(short u) {
  union { unsigned int i; float f; } v;
  v.i = ((unsigned int)(unsigned short)u) << 16;
  return v.f;
}
__device__ __forceinline__ short f2bf(float f) {
  union { float f; unsigned int i; } v;
  v.f = f;
  unsigned int x = v.i;
  unsigned int r = (x + 0x7fffu + ((x >> 16) & 1u)) >> 16;  // RTNE
  return (short)(unsigned short)r;
}
__device__ __forceinline__ float fast_sigmoid(float x) {
  return __builtin_amdgcn_rcpf(1.f + __expf(-x));
}
__device__ __forceinline__ float fast_tanh(float x) {
  const float t = __expf(-2.f * fabsf(x));
  const float th = (1.f - t) * __builtin_amdgcn_rcpf(1.f + t);
  return __builtin_copysignf(th, x);
}

// Async global->LDS DMA, 16 bytes/lane; LDS dest = wave-uniform base+lane*16.
__device__ __forceinline__ void gload16(const void* g, void* l) {
  __builtin_amdgcn_global_load_lds(
      (__attribute__((address_space(1))) void*)g,
      (__attribute__((address_space(3))) void*)l, 16, 0, 0);
}

// C[M,Nc] = A[M,K] * Bw[Nc,K]^T, bf16 in memory, fp32 accum.
// 128x128 tile, BK=32, 512 threads = 8 waves (2x4), wave 64x32 via 4x2
// mfma_f32_16x16x32_bf16. Verified layouts (m89/m91):
//   A/B frag: row/col = lane&15, k = (lane>>4)*8 + j
//   C/D:      col = lane&15, row = (lane>>4)*4 + r
// LDS chunk swizzle: row-slot r stores global k-chunk q at position
// (q + (r>>1)) & 3 -> conflict-free ds_read_b128, DMA-legal lane-linear dest.
// EPI_AVU3: blockIdx.z < 2C -> adjacency slice (batch z>>1, inM/outM by z&1,
// K=N_); z >= 2C -> U3 GEMM for batch z-2C (K=D_).
template <int EPI>
__global__ __launch_bounds__(512, 4) void gemm_nt(
    const short* A, const short* A2, int lda,
    const short* Bw, const short* Bw2, const short* Bw3, int ldb, int Kin,
    const float* bias0, const float* bias1, const float* bias2,
    const short* u3, const short* fcur,   // may alias out0 (in-place G4)
    const short* hvp, const short* zvp,
    short* out0, short* out1, short* out2,
    float* outf, int twoC) {               // EPI_G4 final step: fp32 d_out
  __shared__ __align__(16) short lds_a[128 * 32];   // 8 KB
  __shared__ __align__(16) short lds_b[128 * 32];   // 8 KB

  const int tid = threadIdx.x;
  const int lane = tid & 63;
  const int wave = tid >> 6;          // 0..7
  const int wr = wave >> 2;           // 0..1 (64-row band)
  const int wc = wave & 3;            // 0..3 (32-col band)

  // ---- XCD-aware swizzle (assumes linear-block -> XCD = id % 8) ----
  int bx = blockIdx.x, by = blockIdx.y, bz = blockIdx.z;
  if constexpr (EPI == EPI_AVU3) {
    const int total = gridDim.x * gridDim.y * gridDim.z;
    const int id = (bz * gridDim.y + by) * gridDim.x + bx;
    if ((total & 7) == 0) {
      const int a = id & 7, m = id >> 3;
      const int l = a * (total >> 3) + m;
      bx = l & 3;                 // gx = 4
      by = (l >> 2) & 7;          // gy = 8
      bz = l >> 5;
    }
  } else {
    const int gx = gridDim.x, gy = gridDim.y;
    if ((gy & 7) == 0) {
      const int id = by * gx + bx;
      const int a = id & 7;
      const int m = id >> 3;
      const int per = gy >> 3;
      by = a * per + m / gx;
      bx = m % gx;
    }
  }

  int m0 = by * 128;
  const int n0 = bx * 128;
  int K = Kin;

  const short* Aeff = A;
  const short* Beff = Bw;
  int lda_e = lda, ldb_e = ldb;
  int nb0 = n0;
  bool isU3 = false;
  int b_ = 0, j_ = 0;
  if constexpr (EPI == EPI_AVU3) {
    if (bz < twoC) {               // adjacency slice
      b_ = bz >> 1;
      j_ = bz & 1;
      Aeff = j_ ? A2 : A;                              // inM / outM
      Beff = Bw + (size_t)b_ * ((size_t)D_ * N_);      // T for batch b_
      lda_e = N_; ldb_e = N_; K = N_;
    } else {                       // U3 slice for batch bz-twoC
      isU3 = true;
      const int b = bz - twoC;
      Aeff = u3 /*nodes base*/ + (size_t)b * N_ * D_;
      Beff = Bw3 /*w3u*/;
      lda_e = D_; ldb_e = D_; K = D_;
      b_ = b;
    }
  } else if constexpr (EPI == EPI_BIG) {
    if (n0 < 512) { Beff = Bw; nb0 = n0; }
    else if (n0 < 1024) { Beff = Bw2; nb0 = n0 - 512; }
    else { Beff = Bw3; nb0 = n0 - 1024; }
  }

  f32x4 acc[4][2];
#pragma unroll
  for (int i = 0; i < 4; i++)
#pragma unroll
    for (int j = 0; j < 2; j++) acc[i][j] = (f32x4){0.f, 0.f, 0.f, 0.f};

  const int ar = tid >> 2;                    // row-slot 0..127
  const int sc = tid & 3;                     // stored chunk position
  const int qg = (sc - (ar >> 1)) & 3;        // global k-chunk (conflict-free)
  const int ac = qg * 8;
  char* la = (char*)lds_a + tid * 16;         // tid*16 spans full 8 KB panel
  char* lb = (char*)lds_b + tid * 16;
  const short* ga0 = Aeff + (size_t)(m0 + ar) * lda_e + ac;
  const short* gb0 = Beff + (size_t)(nb0 + ar) * ldb_e + ac;

  const int lm = lane & 15;
  const int qq = lane >> 4;

  // hoisted loop-invariant LDS frag byte offsets
  int offA[4], offB[2];
#pragma unroll
  for (int i = 0; i < 4; i++) {
    const int Ra = wr * 64 + i * 16 + lm;
    offA[i] = Ra * 64 + (((qq + (Ra >> 1)) & 3) << 4);
  }
#pragma unroll
  for (int j = 0; j < 2; j++) {
    const int Rb = wc * 32 + j * 16 + lm;
    offB[j] = Rb * 64 + (((qq + (Rb >> 1)) & 3) << 4);
  }

  for (int k0 = 0; k0 < K; k0 += 32) {
    __syncthreads();
    gload16(ga0 + k0, la);
    gload16(gb0 + k0, lb);
    __syncthreads();

    short8 af[4], bfr[2];
#pragma unroll
    for (int i = 0; i < 4; i++)
      af[i] = *(const short8*)((const char*)lds_a + offA[i]);
#pragma unroll
    for (int j = 0; j < 2; j++)
      bfr[j] = *(const short8*)((const char*)lds_b + offB[j]);
#pragma unroll
    for (int i = 0; i < 4; i++)
#pragma unroll
      for (int j = 0; j < 2; j++)
        acc[i][j] = __builtin_amdgcn_mfma_f32_16x16x32_bf16(
            af[i], bfr[j], acc[i][j], 0, 0, 0);
  }

  const int r0 = (lane >> 4) * 4;
#pragma unroll
  for (int i = 0; i < 4; i++) {
#pragma unroll
    for (int j = 0; j < 2; j++) {
#pragma unroll
      for (int r = 0; r < 4; r++) {
        const int grow = m0 + wr * 64 + i * 16 + r0 + r;
        const int gcol = n0 + wc * 32 + j * 16 + lm;
        const float v = acc[i][j][r];
        if constexpr (EPI == EPI_AVU3) {
          if (!isU3) {
            out0[((size_t)(b_ * N_ + grow)) * TWO_D + j_ * D_ + gcol] =
                f2bf(v);
          } else {
            out1[((size_t)(b_ * N_ + grow)) * D_ + gcol] =
                f2bf(v + bias0[gcol]);
          }
        } else if constexpr (EPI == EPI_BIG) {
          if (gcol < 512) {
            const size_t sidx = (size_t)grow * D_ + gcol;
            const float x = v + bias0[gcol] + bf2f(u3[sidx]);
            out0[sidx] = f2bf(fast_sigmoid(x));
          } else if (gcol < 1024) {
            const int e = gcol - 512;
            const size_t sidx = (size_t)grow * D_ + e;
            const float x = v + bias1[e] + bf2f(u3[sidx]);
            out1[sidx] = f2bf(fast_sigmoid(x) * bf2f(fcur[sidx]));
          } else {
            const int e = gcol - 1024;
            const size_t sidx = (size_t)grow * D_ + e;
            out2[sidx] = f2bf(v + bias2[e]);
          }
        } else {  // EPI_G4 (in-place: same thread reads then writes sidx)
          const size_t sidx = (size_t)grow * D_ + gcol;
          const float x = bf2f(hvp[sidx]) + v + bias0[gcol];
          const float hv = fast_tanh(x);
          const float z = bf2f(zvp[sidx]);
          const float f = bf2f(fcur[sidx]);
          const float res = (1.f - z) * f + z * hv;
          if (outf) outf[sidx] = res;      // final step: fp32 to d_out
          else out0[sidx] = f2bf(res);     // intermediate: bf16 nodes update
        }
      }
    }
  }
}

// bf16 [C][N][D] -> bf16 [C][D][N] transpose.
__global__ void transpose_bnd(const short* __restrict__ in,
                              short* __restrict__ out) {
  __shared__ short tile[32][33];
  const int b = blockIdx.z;
  const int n0 = blockIdx.y * 32;
  const int d0 = blockIdx.x * 32;
  const int tx = threadIdx.x, ty = threadIdx.y;
  const short* ip = in + (size_t)b * N_ * D_;
  short* op = out + (size_t)b * N_ * D_;
#pragma unroll
  for (int yy = ty; yy < 32; yy += 8)
    tile[yy][tx] = ip[(size_t)(n0 + yy) * D_ + d0 + tx];
  __syncthreads();
#pragma unroll
  for (int yy = ty; yy < 32; yy += 8)
    op[(size_t)(d0 + yy) * N_ + n0 + tx] = tile[tx][yy];
}

// One-shot segmented fp32->bf16 convert (8 jobs, grid-stride over v4 elems).
struct CvtJobs {
  const float* src[8];
  short* dst[8];
  int end4[8];
  int tot4;
};
__global__ void cvt_all(CvtJobs j) {
  for (int idx = blockIdx.x * 256 + threadIdx.x; idx < j.tot4;
       idx += gridDim.x * 256) {
    int k = 0, start = 0;
#pragma unroll
    for (int t = 0; t < 8; t++) {
      if (idx >= j.end4[t]) { k = t + 1; start = j.end4[t]; }
    }
    const int rel = idx - start;
    const f32x4 v = ((const f32x4*)j.src[k])[rel];
    s16x4 o;
#pragma unroll
    for (int r = 0; r < 4; r++) o[r] = f2bf(v[r]);
    ((s16x4*)j.dst[k])[rel] = o;
  }
}

extern "C" void kernel_launch(void* const* d_in, const int* in_sizes, int n_in,
                              void* d_out, int out_size, void* d_ws,
                              size_t ws_size, hipStream_t stream) {
  const float* x = (const float*)d_in[0];
  const float* inM = (const float*)d_in[1];
  const float* outM = (const float*)d_in[2];
  const float* w3w = (const float*)d_in[3];
  const float* b3w = (const float*)d_in[4];
  const float* w3u = (const float*)d_in[5];
  const float* b3u = (const float*)d_in[6];
  const float* w4w = (const float*)d_in[7];
  const float* b4w = (const float*)d_in[8];
  const float* w5w = (const float*)d_in[9];
  const float* b5w = (const float*)d_in[10];
  const float* w5u = (const float*)d_in[11];
  const float* b5u = (const float*)d_in[12];
  float* outF = (float*)d_out;   // fp32 output: nodes [S_,D_] ++ in_matrix

  char* ws = (char*)d_ws;
  size_t off = 0;
  auto alloc = [&](size_t elems) {
    short* p = (short*)(ws + off);
    off = (off + elems * 2 + 255) & ~(size_t)255;
    return p;
  };
  short* nodes = alloc((size_t)S_ * D_);           // bf16 recursion state
  short* inMb = alloc((size_t)N_ * N_);
  short* outMb = alloc((size_t)N_ * N_);
  short* w3wb = alloc((size_t)512 * 1024);
  short* w4wb = alloc((size_t)512 * 1024);
  short* w5wb = alloc((size_t)512 * 1024);
  short* w3ub = alloc((size_t)D_ * D_);
  short* w5ub = alloc((size_t)D_ * D_);
  const size_t fixed = off;

  // chunk size C: per-chunk scratch = T+av+u3+zv+rf+hvp = 7*C*N*D bf16
  int C = 1;
  for (int c = 16; c >= 1; c >>= 1) {
    const size_t need = fixed + (size_t)7 * c * N_ * D_ * 2 + 8 * 256;
    if (need <= ws_size) { C = c; break; }
  }
  short* T = alloc((size_t)C * D_ * N_);
  short* av = alloc((size_t)C * N_ * TWO_D);
  short* u3 = alloc((size_t)C * N_ * D_);
  short* zv = alloc((size_t)C * N_ * D_);
  short* rf = alloc((size_t)C * N_ * D_);
  short* hvp = alloc((size_t)C * N_ * D_);

  // --- one fused convert launch: fp32 -> bf16 working set ---
  CvtJobs cj;
  const int xs4 = S_ * D_ / 4, nn4 = N_ * N_ / 4;
  const int dd4 = D_ * D_ / 4, wd4 = 512 * 1024 / 4;
  const float* srcs[8] = {x, inM, outM, w3w, w4w, w5w, w3u, w5u};
  short* dsts[8] = {nodes, inMb, outMb, w3wb, w4wb, w5wb, w3ub, w5ub};
  const int lens[8] = {xs4, nn4, nn4, wd4, wd4, wd4, dd4, dd4};
  int cum = 0;
  for (int i = 0; i < 8; i++) {
    cj.src[i] = srcs[i];
    cj.dst[i] = dsts[i];
    cum += lens[i];
    cj.end4[i] = cum;
  }
  cj.tot4 = cum;
  cvt_all<<<1536, 256, 0, stream>>>(cj);
  // output 1: in_matrix passthrough (fp32 bit copy)
  hipMemcpyAsync(outF + (size_t)S_ * D_, inM, (size_t)N_ * N_ * 4,
                 hipMemcpyDeviceToDevice, stream);

  const dim3 tb32(32, 8);
  const dim3 tg(D_ / 32, N_ / 32, C);
  const dim3 g_avu3(D_ / 128, N_ / 128, 3 * C);   // AV (2C) + U3 (C)
  const dim3 g_d(D_ / 128, C * N_ / 128, 1);
  const dim3 g_big(1536 / 128, C * N_ / 128, 1);

  const int nchunks = B_ / C;
  for (int c = 0; c < nchunks; ++c) {
    short* nodes_c = nodes + (size_t)c * C * N_ * D_;
    float* outF_c = outF + (size_t)c * C * N_ * D_;
    for (int step = 0; step < 3; ++step) {
      transpose_bnd<<<tg, tb32, 0, stream>>>(nodes_c, T);
      gemm_nt<EPI_AVU3><<<g_avu3, 512, 0, stream>>>(
          inMb, outMb, N_, T, nullptr, w3ub, N_, N_, b3u, nullptr, nullptr,
          nodes_c, nullptr, nullptr, nullptr, av, u3, nullptr, nullptr,
          2 * C);
      gemm_nt<EPI_BIG><<<g_big, 512, 0, stream>>>(
          av, nullptr, TWO_D, w3wb, w4wb, w5wb, TWO_D, TWO_D, b3w, b4w, b5w,
          u3, nodes_c, nullptr, nullptr, zv, rf, hvp, nullptr, 0);
      float* outf = (step == 2) ? outF_c : nullptr;
      gemm_nt<EPI_G4><<<g_d, 512, 0, stream>>>(
          rf, nullptr, D_, w5ub, nullptr, nullptr, D_, D_, b5u, nullptr,
          nullptr, nullptr, nodes_c, hvp, zv, nodes_c, nullptr, nullptr,
          outf, 0);
    }
  }
}